// Round 4
// baseline (947.871 us; speedup 1.0000x reference)
//
#include <hip/hip_runtime.h>

// Problem constants: flow/flowback [B,2,T,H,W] fp32, masks [B,1,T,H,W] fp32.
#define BB 8
#define TT 8
#define HH 512
#define WW 512
#define HWSZ (HH * WW)                    // 262144 pixels per (b,t) slice
#define NSL  (BB * TT)                    // 64 slices
#define TOTAL_ELEMS 33554432.0            // B*C*T*H*W (mean denom)

#define SLICE_FLOATS (HWSZ * 2)           // interleaved slice: 512K floats = 2 MB
#define ACC_OFF      0
#define FI_OFF       512                                       // bytes
#define GI_OFF       (FI_OFF + (size_t)NSL * SLICE_FLOATS * 4) // bytes
#define WS_NEEDED    (GI_OFF + (size_t)NSL * SLICE_FLOATS * 4) // ~268.4 MB

// Unaligned-tolerant loads.
__device__ __forceinline__ float2 ld2(const float* __restrict__ p) {
    float2 v; __builtin_memcpy(&v, p, sizeof(float2)); return v;
}
__device__ __forceinline__ float4 ld4u(const float* __restrict__ p) {
    float4 v; __builtin_memcpy(&v, p, sizeof(float4)); return v;
}

// ---------------- repack: planar [b][c][t][H][W] -> interleaved [s][H][W][2] ----
__global__ __launch_bounds__(256, 8) void repack_kernel(
    const float* __restrict__ flow,
    const float* __restrict__ flowback,
    float* __restrict__ fi,
    float* __restrict__ gi)
{
    // blockIdx = s * 256 + o ; thread handles one float4 quad (4 px) of slice s.
    const int s = blockIdx.x >> 8;
    const int o = blockIdx.x & 255;
    const int b = s >> 3;
    const int t = s & 7;
    const int pix = (o * 256 + threadIdx.x) * 4;

    const int ps = (b * 16 + t) * HWSZ;      // planar ch0 plane offset
    {
        const float4 c0 = *(const float4*)(flow + ps + pix);
        const float4 c1 = *(const float4*)(flow + ps + 8 * HWSZ + pix);
        float* d = fi + (size_t)s * SLICE_FLOATS + 2 * pix;
        *(float4*)(d)     = make_float4(c0.x, c1.x, c0.y, c1.y);
        *(float4*)(d + 4) = make_float4(c0.z, c1.z, c0.w, c1.w);
    }
    {
        const float4 c0 = *(const float4*)(flowback + ps + pix);
        const float4 c1 = *(const float4*)(flowback + ps + 8 * HWSZ + pix);
        float* d = gi + (size_t)s * SLICE_FLOATS + 2 * pix;
        *(float4*)(d)     = make_float4(c0.x, c1.x, c0.y, c1.y);
        *(float4*)(d + 4) = make_float4(c0.z, c1.z, c0.w, c1.w);
    }
}

// Bilinear sample of an interleaved 2-channel plane [H][W][2]; zeros padding,
// align_corners=True. ONE dwordx4 per row-tap (both channels, both x-taps).
__device__ __forceinline__ void bilin2i(const float* __restrict__ pl,
                                        float sx, float sy,
                                        float& r0, float& r1)
{
    const float x0f = floorf(sx);
    const float y0f = floorf(sy);
    const float wx1 = sx - x0f;
    const float wy1 = sy - y0f;
    const int x0 = (int)x0f;
    const int y0 = (int)y0f;
    const int y1 = y0 + 1;

    const int xl = min(max(x0, 0), WW - 2);
    const float ax = (1.f - wx1) * ((x0 >= 0 && x0 < WW) ? 1.f : 0.f);       // tap x0
    const float bx = wx1 * ((x0 + 1 >= 0 && x0 + 1 < WW) ? 1.f : 0.f);       // tap x0+1
    const bool lo_is_x0 = (x0 == xl);
    const float wl = lo_is_x0 ? ax : bx;
    const float wr = lo_is_x0 ? bx : ax;

    const float wyA = (1.f - wy1) * ((y0 >= 0 && y0 < HH) ? 1.f : 0.f);
    const float wyB = wy1 * ((y1 >= 0 && y1 < HH) ? 1.f : 0.f);
    const int ycA = min(max(y0, 0), HH - 1);
    const int ycB = min(max(y1, 0), HH - 1);

    // [c0(xl), c1(xl), c0(xl+1), c1(xl+1)] per row, 8B-aligned 16B load
    const float4 a = ld4u(pl + 2 * (ycA * WW + xl));
    const float4 b = ld4u(pl + 2 * (ycB * WW + xl));

    r0 = wyA * (wl * a.x + wr * a.z) + wyB * (wl * b.x + wr * b.z);
    r1 = wyA * (wl * a.y + wr * a.w) + wyB * (wl * b.y + wr * b.w);
}

// Grid: 2048 blocks x 256 threads; blockIdx&7 = XCD; 256 blocks/XCD sweep the
// XCD's 8 slices one at a time (per-XCD gather working set ~4MB interleaved).
__global__ __launch_bounds__(256, 8) void flow_loss_i_kernel(
    const float* __restrict__ fi,
    const float* __restrict__ gi,
    const float* __restrict__ mask_fw,
    const float* __restrict__ mask_bw,
    double* __restrict__ acc)
{
    const int xcd = blockIdx.x & 7;
    const int o   = blockIdx.x >> 3;          // 0..255
    const int g   = o * 256 + threadIdx.x;    // quad index in slice
    const int pix = g * 4;
    const int xb  = pix & (WW - 1);
    const int y   = pix >> 9;

    float lsum = 0.f;

    for (int sl = 0; sl < 8; ++sl) {
        const int s = xcd * 8 + sl;
        const float* fp = fi + (size_t)s * SLICE_FLOATS;
        const float* gp = gi + (size_t)s * SLICE_FLOATS;
        const float* mfp = mask_fw + (size_t)s * HWSZ;
        const float* mbp = mask_bw + (size_t)s * HWSZ;

        // streams (all 16B/32B aligned)
        const float4 f01 = *(const float4*)(fp + 2 * pix);       // fx0,fy0,fx1,fy1
        const float4 f23 = *(const float4*)(fp + 2 * pix + 4);
        const float4 g01 = *(const float4*)(gp + 2 * pix);
        const float4 g23 = *(const float4*)(gp + 2 * pix + 4);
        const float4 mfv = *(const float4*)(mfp + pix);
        const float4 mbv = *(const float4*)(mbp + pix);

        const float fxa[4] = {f01.x, f01.z, f23.x, f23.z};
        const float fya[4] = {f01.y, f01.w, f23.y, f23.w};
        const float gxa[4] = {g01.x, g01.z, g23.x, g23.z};
        const float gya[4] = {g01.y, g01.w, g23.y, g23.w};
        const float mfa[4] = {mfv.x, mfv.y, mfv.z, mfv.w};
        const float mba[4] = {mbv.x, mbv.y, mbv.z, mbv.w};

#pragma unroll
        for (int k = 0; k < 4; ++k) {
            const float xf = (float)(xb + k);
            const float yf = (float)y;
            float wfbx, wfby, wfx, wfy;
            // nextloss: warp(flowback, flow) + flow
            bilin2i(gp, xf + fxa[k], yf + fya[k], wfbx, wfby);
            // prevloss: warp(flow, flowback) + flowback
            bilin2i(fp, xf + gxa[k], yf + gya[k], wfx, wfy);
            lsum += mfa[k] * (fabsf(wfbx + fxa[k]) + fabsf(wfby + fya[k]))
                  + mba[k] * (fabsf(wfx  + gxa[k]) + fabsf(wfy  + gya[k]));
        }
    }

    for (int off = 32; off > 0; off >>= 1)
        lsum += __shfl_down(lsum, off, 64);

    __shared__ float wsum[4];
    const int lane = threadIdx.x & 63;
    const int wv   = threadIdx.x >> 6;
    if (lane == 0) wsum[wv] = lsum;
    __syncthreads();
    if (threadIdx.x == 0) {
        float ssum = wsum[0] + wsum[1] + wsum[2] + wsum[3];
        atomicAdd(acc, (double)ssum);
    }
}

// ---------------- fallback (R3 planar path) if ws_size < WS_NEEDED -----------
__device__ __forceinline__ void bilin2p(const float* __restrict__ c0,
                                        const float* __restrict__ c1,
                                        float sx, float sy,
                                        float& r0, float& r1)
{
    const float x0f = floorf(sx);
    const float y0f = floorf(sy);
    const float wx1 = sx - x0f;
    const float wy1 = sy - y0f;
    const int x0 = (int)x0f;
    const int y0 = (int)y0f;
    const int y1 = y0 + 1;
    const int xl = min(max(x0, 0), WW - 2);
    const float ax = (1.f - wx1) * ((x0 >= 0 && x0 < WW) ? 1.f : 0.f);
    const float bx = wx1 * ((x0 + 1 >= 0 && x0 + 1 < WW) ? 1.f : 0.f);
    const bool lo_is_x0 = (x0 == xl);
    const float wl = lo_is_x0 ? ax : bx;
    const float wr = lo_is_x0 ? bx : ax;
    const float wyA = (1.f - wy1) * ((y0 >= 0 && y0 < HH) ? 1.f : 0.f);
    const float wyB = wy1 * ((y1 >= 0 && y1 < HH) ? 1.f : 0.f);
    const int baseA = (min(max(y0, 0), HH - 1)) * WW + xl;
    const int baseB = (min(max(y1, 0), HH - 1)) * WW + xl;
    const float2 a0 = ld2(c0 + baseA);
    const float2 b0 = ld2(c0 + baseB);
    const float2 a1 = ld2(c1 + baseA);
    const float2 b1 = ld2(c1 + baseB);
    r0 = wyA * (wl * a0.x + wr * a0.y) + wyB * (wl * b0.x + wr * b0.y);
    r1 = wyA * (wl * a1.x + wr * a1.y) + wyB * (wl * b1.x + wr * b1.y);
}

__global__ __launch_bounds__(256, 6) void flow_loss_p_kernel(
    const float* __restrict__ flow,
    const float* __restrict__ flowback,
    const float* __restrict__ mask_fw,
    const float* __restrict__ mask_bw,
    double* __restrict__ acc)
{
    const int xcd = blockIdx.x & 7;
    const int o   = blockIdx.x >> 3;
    const int g   = o * 256 + threadIdx.x;
    const int pix = g * 4;
    const int xb  = pix & (WW - 1);
    const int y   = pix >> 9;
    float lsum = 0.f;
    for (int sl = 0; sl < 8; ++sl) {
        const int s = xcd * 8 + sl;
        const int b = s >> 3;
        const int t = s & 7;
        const float* f0 = flow     + (b * 16 + t) * HWSZ;
        const float* f1 = f0 + 8 * HWSZ;
        const float* g0 = flowback + (b * 16 + t) * HWSZ;
        const float* g1 = g0 + 8 * HWSZ;
        const float* mfp = mask_fw + s * HWSZ;
        const float* mbp = mask_bw + s * HWSZ;
        const float4 fxv = *(const float4*)(f0 + pix);
        const float4 fyv = *(const float4*)(f1 + pix);
        const float4 gxv = *(const float4*)(g0 + pix);
        const float4 gyv = *(const float4*)(g1 + pix);
        const float4 mfv = *(const float4*)(mfp + pix);
        const float4 mbv = *(const float4*)(mbp + pix);
        const float fxa[4] = {fxv.x, fxv.y, fxv.z, fxv.w};
        const float fya[4] = {fyv.x, fyv.y, fyv.z, fyv.w};
        const float gxa[4] = {gxv.x, gxv.y, gxv.z, gxv.w};
        const float gya[4] = {gyv.x, gyv.y, gyv.z, gyv.w};
        const float mfa[4] = {mfv.x, mfv.y, mfv.z, mfv.w};
        const float mba[4] = {mbv.x, mbv.y, mbv.z, mbv.w};
#pragma unroll
        for (int k = 0; k < 4; ++k) {
            const float xf = (float)(xb + k);
            const float yf = (float)y;
            float wfbx, wfby, wfx, wfy;
            bilin2p(g0, g1, xf + fxa[k], yf + fya[k], wfbx, wfby);
            bilin2p(f0, f1, xf + gxa[k], yf + gya[k], wfx, wfy);
            lsum += mfa[k] * (fabsf(wfbx + fxa[k]) + fabsf(wfby + fya[k]))
                  + mba[k] * (fabsf(wfx  + gxa[k]) + fabsf(wfy  + gya[k]));
        }
    }
    for (int off = 32; off > 0; off >>= 1)
        lsum += __shfl_down(lsum, off, 64);
    __shared__ float wsum[4];
    const int lane = threadIdx.x & 63;
    const int wv   = threadIdx.x >> 6;
    if (lane == 0) wsum[wv] = lsum;
    __syncthreads();
    if (threadIdx.x == 0) {
        float ssum = wsum[0] + wsum[1] + wsum[2] + wsum[3];
        atomicAdd(acc, (double)ssum);
    }
}

__global__ void finalize_kernel(const double* __restrict__ acc,
                                const int* __restrict__ npf,
                                float* __restrict__ out)
{
    out[0] = (float)(acc[0] * ((double)npf[0] / TOTAL_ELEMS));
}

extern "C" void kernel_launch(void* const* d_in, const int* in_sizes, int n_in,
                              void* d_out, int out_size, void* d_ws, size_t ws_size,
                              hipStream_t stream)
{
    const float* flow     = (const float*)d_in[0];
    const float* flowback = (const float*)d_in[1];
    const float* mask_fw  = (const float*)d_in[2];
    const float* mask_bw  = (const float*)d_in[3];
    const int*   npf      = (const int*)d_in[4];
    float*  out = (float*)d_out;
    double* acc = (double*)d_ws;

    hipMemsetAsync(d_ws, 0, sizeof(double), stream);

    if (ws_size >= WS_NEEDED) {
        float* fi = (float*)((char*)d_ws + FI_OFF);
        float* gi = (float*)((char*)d_ws + GI_OFF);
        repack_kernel<<<NSL * 256, 256, 0, stream>>>(flow, flowback, fi, gi);
        flow_loss_i_kernel<<<2048, 256, 0, stream>>>(fi, gi, mask_fw, mask_bw, acc);
    } else {
        flow_loss_p_kernel<<<2048, 256, 0, stream>>>(flow, flowback, mask_fw, mask_bw, acc);
    }
    finalize_kernel<<<1, 1, 0, stream>>>(acc, npf, out);
}